// Round 7
// baseline (249.042 us; speedup 1.0000x reference)
//
#include <hip/hip_runtime.h>
#include <hip/hip_fp16.h>

#define NN 512
#define DD 768

typedef _Float16 half8 __attribute__((ext_vector_type(8)));
typedef _Float16 half4 __attribute__((ext_vector_type(4)));
typedef _Float16 half2v __attribute__((ext_vector_type(2)));
typedef float f32x4 __attribute__((ext_vector_type(4)));

__device__ __forceinline__ int f2ord(float f) {
  int i = __float_as_int(f);
  return i < 0 ? (i ^ 0x7fffffff) : i;
}
__device__ __forceinline__ float ord2f(int i) {
  return __int_as_float(i < 0 ? (i ^ 0x7fffffff) : i);
}

// async global->LDS, 16B per lane; LDS dest must be wave-uniform base (lane*16 implicit)
__device__ __forceinline__ void glds16(const void* g, void* l) {
  __builtin_amdgcn_global_load_lds((const __attribute__((address_space(1))) void*)g,
                                   (__attribute__((address_space(3))) void*)l, 16, 0, 0);
}

// ---------------- K0: init min/max meta ----------------
__global__ void k_init(int* meta) {
  if (threadIdx.x == 0) {
    meta[0] = 0x7fffffff;  // ordered-int +max (min accumulator)
    meta[1] = 0x80000000;  // ordered-int -max (max accumulator)
  }
}

// ---------------- K1: row-normalize + fp16 cast ----------------
__global__ __launch_bounds__(256) void k_norm(const float* __restrict__ f1,
                                              const float* __restrict__ f2,
                                              __half* __restrict__ xn,
                                              __half* __restrict__ yn) {
  int row = blockIdx.x * 4 + (threadIdx.x >> 6);
  int lane = threadIdx.x & 63;
  int r = row & 32767;
  const float* src = (row < 32768 ? f1 : f2) + (size_t)r * DD;
  __half* dst = (row < 32768 ? xn : yn) + (size_t)r * DD;
  f32x4 v0 = *(const f32x4*)(src + lane * 4);
  f32x4 v1 = *(const f32x4*)(src + lane * 4 + 256);
  f32x4 v2 = *(const f32x4*)(src + lane * 4 + 512);
  float s = v0[0]*v0[0] + v0[1]*v0[1] + v0[2]*v0[2] + v0[3]*v0[3]
          + v1[0]*v1[0] + v1[1]*v1[1] + v1[2]*v1[2] + v1[3]*v1[3]
          + v2[0]*v2[0] + v2[1]*v2[1] + v2[2]*v2[2] + v2[3]*v2[3];
  #pragma unroll
  for (int m = 1; m < 64; m <<= 1) s += __shfl_xor(s, m, 64);
  float f = 1.0f / (sqrtf(s) + 1e-12f);
  union U { __half2 h2[2]; uint2 u; };
  U u0, u1, u2;
  u0.h2[0] = __floats2half2_rn(v0[0]*f, v0[1]*f); u0.h2[1] = __floats2half2_rn(v0[2]*f, v0[3]*f);
  u1.h2[0] = __floats2half2_rn(v1[0]*f, v1[1]*f); u1.h2[1] = __floats2half2_rn(v1[2]*f, v1[3]*f);
  u2.h2[0] = __floats2half2_rn(v2[0]*f, v2[1]*f); u2.h2[1] = __floats2half2_rn(v2[2]*f, v2[3]*f);
  *(uint2*)(dst + lane * 4)       = u0.u;
  *(uint2*)(dst + lane * 4 + 256) = u1.u;
  *(uint2*)(dst + lane * 4 + 512) = u2.u;
}

// ---------------- K2: batched fp16 MFMA GEMM via global_load_lds double-buffer ----------
__global__ __launch_bounds__(256) void k_gemm(const __half* __restrict__ xn,
                                              const __half* __restrict__ yn,
                                              float* __restrict__ cosm,
                                              int* __restrict__ meta) {
  __shared__ __align__(16) __half As[2][4096];  // [128][32] per buffer
  __shared__ __align__(16) __half Bs[2][4096];
  __shared__ float rmin[4], rmax[4];
  const int b  = blockIdx.y;
  const int ti = blockIdx.x >> 2;
  const int tj = blockIdx.x & 3;
  const int tid = threadIdx.x;
  const int wv = tid >> 6, lane = tid & 63;
  const int wr = (wv >> 1) * 64, wc = (wv & 1) * 64;
  const __half* Ab = xn + ((size_t)b * NN + (size_t)ti * 128) * DD;
  const __half* Bb = yn + ((size_t)b * NN + (size_t)tj * 128) * DD;
  const int srow = tid >> 2;
  const int scol = (tid & 3) * 8;
  const __half* ga0 = Ab + (size_t)srow * DD + scol;
  const __half* ga1 = ga0 + (size_t)64 * DD;
  const __half* gb0 = Bb + (size_t)srow * DD + scol;
  const __half* gb1 = gb0 + (size_t)64 * DD;
  f32x4 acc[4][4] = {};
  const int fr = lane & 15;
  const int kb = (lane >> 4) * 8;

  // stage one 32-wide K-slab into buffer bf; LDS layout byte off = tid*16 (+4096 for rows 64+)
#define STAGE(bf, kk) { \
    glds16(ga0 + (kk), &As[bf][wv * 512]); \
    glds16(ga1 + (kk), &As[bf][2048 + wv * 512]); \
    glds16(gb0 + (kk), &Bs[bf][wv * 512]); \
    glds16(gb1 + (kk), &Bs[bf][2048 + wv * 512]); }

  int buf = 0;
  STAGE(0, 0)
  for (int kk = 0; kk < DD; kk += 32) {
    __syncthreads();  // drains vmcnt: current slab resident; prev compute finished
    if (kk + 32 < DD) STAGE(buf ^ 1, kk + 32)  // prefetch overlaps MFMA below
    half8 af[4], bf4[4];
    #pragma unroll
    for (int g = 0; g < 4; ++g) {
      af[g]  = *(const half8*)(&As[buf][(wr + g * 16 + fr) * 32 + kb]);
      bf4[g] = *(const half8*)(&Bs[buf][(wc + g * 16 + fr) * 32 + kb]);
    }
    #pragma unroll
    for (int g = 0; g < 4; ++g) {
      #pragma unroll
      for (int h = 0; h < 4; ++h) {
        acc[g][h] = __builtin_amdgcn_mfma_f32_16x16x32_f16(af[g], bf4[h], acc[g][h], 0, 0, 0);
      }
    }
    buf ^= 1;
  }
  float vmin = 1e30f, vmax = -1e30f;
  float* cb = cosm + (size_t)b * NN * NN;
  #pragma unroll
  for (int g = 0; g < 4; ++g) {
    #pragma unroll
    for (int h = 0; h < 4; ++h) {
      #pragma unroll
      for (int r2 = 0; r2 < 4; ++r2) {
        int row = ti * 128 + wr + g * 16 + (lane >> 4) * 4 + r2;
        int col = tj * 128 + wc + h * 16 + fr;
        float val = 1.0f - acc[g][h][r2];
        cb[(size_t)row * NN + col] = val;
        vmin = fminf(vmin, val); vmax = fmaxf(vmax, val);
      }
    }
  }
  #pragma unroll
  for (int m = 1; m < 64; m <<= 1) {
    vmin = fminf(vmin, __shfl_xor(vmin, m, 64));
    vmax = fmaxf(vmax, __shfl_xor(vmax, m, 64));
  }
  if (lane == 0) { rmin[wv] = vmin; rmax[wv] = vmax; }
  __syncthreads();
  if (tid == 0) {
    float bm = fminf(fminf(rmin[0], rmin[1]), fminf(rmin[2], rmin[3]));
    float bx = fmaxf(fmaxf(rmax[0], rmax[1]), fmaxf(rmax[2], rmax[3]));
    atomicMin(meta + 0, f2ord(bm));
    atomicMax(meta + 1, f2ord(bx));
  }
}

// ---------------- K3: 30 IPOT iterations, 4 blocks/batch, A/M in NAMED half8 registers ----
// Cross-block exchange via iteration-indexed inbox slots with sign-bit-encoded values:
//   writer: store bits|0x80000000 (exact decode via mask; works for 0.0 partials)
//   reader: poll 8 partner words until all negative ints -> decode+sum. ONE round-trip,
//   no counter, no fences, no slot reuse (slots zeroed by memsetAsync before launch).
#define FOR16(X) X(0) X(1) X(2) X(3) X(4) X(5) X(6) X(7) X(8) X(9) X(10) X(11) X(12) X(13) X(14) X(15)

#define AGLD(p) __hip_atomic_load((p), __ATOMIC_RELAXED, __HIP_MEMORY_SCOPE_AGENT)
#define AGST(p, v) __hip_atomic_store((p), (v), __ATOMIC_RELAXED, __HIP_MEMORY_SCOPE_AGENT)

__global__ __launch_bounds__(512, 2) void k_ipot(const float* __restrict__ cosm,
                                                 const int* __restrict__ meta,
                                                 unsigned* __restrict__ gx,
                                                 float* __restrict__ gdist) {
  __shared__ float xs[128];
  __shared__ float ys[NN];
  __shared__ __align__(16) _Float16 zs[NN];
  __shared__ __align__(16) _Float16 csh[8][520];
  __shared__ float wred[8];
  const int blk = blockIdx.x;
  const int b = blk & 63, qq = blk >> 6;  // 4 partner blocks land on same XCD
  const int tid = threadIdx.x;
  const int w = tid >> 6, lane = tid & 63;
  const int r0 = w * 16;
  const int c0 = lane * 8;
  const float* cb = cosm + (size_t)b * NN * NN + (size_t)(qq * 128) * NN;
  const float gmn = ord2f(meta[0]);
  const float gmx = ord2f(meta[1]);
  const float thr = gmn + 0.1f * (gmx - gmn);

#define DECLAM(r) half8 A##r, M##r;
  FOR16(DECLAM)

#define INITAM(r) { \
    const float* rp = cb + (size_t)(r0 + r) * NN + c0; \
    f32x4 v0 = *(const f32x4*)rp; \
    f32x4 v1 = *(const f32x4*)(rp + 4); \
    A##r.s0 = (_Float16)__expf(-2.0f * fmaxf(v0[0] - thr, 0.0f)); \
    A##r.s1 = (_Float16)__expf(-2.0f * fmaxf(v0[1] - thr, 0.0f)); \
    A##r.s2 = (_Float16)__expf(-2.0f * fmaxf(v0[2] - thr, 0.0f)); \
    A##r.s3 = (_Float16)__expf(-2.0f * fmaxf(v0[3] - thr, 0.0f)); \
    A##r.s4 = (_Float16)__expf(-2.0f * fmaxf(v1[0] - thr, 0.0f)); \
    A##r.s5 = (_Float16)__expf(-2.0f * fmaxf(v1[1] - thr, 0.0f)); \
    A##r.s6 = (_Float16)__expf(-2.0f * fmaxf(v1[2] - thr, 0.0f)); \
    A##r.s7 = (_Float16)__expf(-2.0f * fmaxf(v1[3] - thr, 0.0f)); \
    M##r = A##r; }
  FOR16(INITAM)

  if (tid < 256) *(half2v*)(zs + 2 * tid) = (half2v){(_Float16)1.0f, (_Float16)1.0f};  // ẑ₁=1
  ys[tid] = 1.0f;  // ŷ₀=1
  __syncthreads();

  #pragma unroll 1
  for (int t = 1; t <= 30; ++t) {
    // ---- row pass: r_i = sum_j M_ij ẑ_j over own 8 cols; x̂ = 1/rowsum ----
    half8 zv = *(const half8*)(zs + c0);
    float rp16[16];
#define ROWP(r) { \
      half8 p = M##r * zv; \
      half4 q = p.lo + p.hi; \
      half2v q2 = q.lo + q.hi; \
      rp16[r] = (float)q2.x + (float)q2.y; }
    FOR16(ROWP)
    float c8[8];
    #pragma unroll
    for (int i = 0; i < 8; ++i) {
      float keep = (lane & 1) ? rp16[2*i+1] : rp16[2*i];
      float send = (lane & 1) ? rp16[2*i]   : rp16[2*i+1];
      c8[i] = keep + __shfl_xor(send, 1, 64);
    }
    float c4[4];
    #pragma unroll
    for (int i = 0; i < 4; ++i) {
      float keep = (lane & 2) ? c8[2*i+1] : c8[2*i];
      float send = (lane & 2) ? c8[2*i]   : c8[2*i+1];
      c4[i] = keep + __shfl_xor(send, 2, 64);
    }
    float d2[2];
    #pragma unroll
    for (int i = 0; i < 2; ++i) {
      float keep = (lane & 4) ? c4[2*i+1] : c4[2*i];
      float send = (lane & 4) ? c4[2*i]   : c4[2*i+1];
      d2[i] = keep + __shfl_xor(send, 4, 64);
    }
    float c1;
    {
      float keep = (lane & 8) ? d2[1] : d2[0];
      float send = (lane & 8) ? d2[0] : d2[1];
      c1 = keep + __shfl_xor(send, 8, 64);
    }
    c1 += __shfl_xor(c1, 16, 64);
    c1 += __shfl_xor(c1, 32, 64);
    if (lane < 16) xs[r0 + lane] = 1.0f / c1;  // wave-local write; same-wave reads below
    // ---- col pass: cac_j = sum over own 16 rows of M*x̂ (xs is wave-local) ----
    half8 cac = (half8)(_Float16)0.0f;
#define COLP(r) { _Float16 xh = (_Float16)xs[r0 + r]; cac += M##r * xh; }
    FOR16(COLP)
    *(half8*)(&csh[w][c0]) = cac;
#define UPDM(r) M##r *= A##r;
    if (t < 30) { FOR16(UPDM) }  // M <- M∘A in regs, overlaps LDS latency
    __syncthreads();
    // ---- block col-reduce -> sign-tagged store -> direct poll of 4 partners ----
    if (tid < 256) {
      float a0 = 0.0f, a1 = 0.0f;
      #pragma unroll
      for (int g = 0; g < 8; ++g) {
        half2v pv = *(const half2v*)(&csh[g][2 * tid]);
        a0 += (float)pv.x; a1 += (float)pv.y;
      }
      unsigned* base = gx + ((size_t)((t - 1) * 64 + b) * 4) * 512 + 2 * tid;
      AGST(base + qq * 512,     __float_as_uint(a0) | 0x80000000u);
      AGST(base + qq * 512 + 1, __float_as_uint(a1) | 0x80000000u);
      unsigned u00, u01, u10, u11, u20, u21, u30, u31;
      for (;;) {
        u00 = AGLD(base);        u01 = AGLD(base + 1);
        u10 = AGLD(base + 512);  u11 = AGLD(base + 513);
        u20 = AGLD(base + 1024); u21 = AGLD(base + 1025);
        u30 = AGLD(base + 1536); u31 = AGLD(base + 1537);
        if ((int)(u00 & u01 & u10 & u11 & u20 & u21 & u30 & u31) < 0) break;
        __builtin_amdgcn_s_sleep(1);
      }
      float s0 = __uint_as_float(u00 & 0x7fffffffu) + __uint_as_float(u10 & 0x7fffffffu)
               + __uint_as_float(u20 & 0x7fffffffu) + __uint_as_float(u30 & 0x7fffffffu);
      float s1 = __uint_as_float(u01 & 0x7fffffffu) + __uint_as_float(u11 & 0x7fffffffu)
               + __uint_as_float(u21 & 0x7fffffffu) + __uint_as_float(u31 & 0x7fffffffu);
      float yo0 = ys[2 * tid], yo1 = ys[2 * tid + 1];
      float y0 = 1.0f / s0;
      float y1 = 1.0f / s1;
      *(half2v*)(zs + 2 * tid) = (half2v){(_Float16)(y0 * y0 / yo0), (_Float16)(y1 * y1 / yo1)};
      ys[2 * tid] = y0; ys[2 * tid + 1] = y1;
    }
    __syncthreads();
  }

  // ---- dist partial = sum_ij relu(C-thr) * M_ij * x̂_i * ŷ_j over own patch ----
  float contrib = 0.0f;
#define FINP(r) { \
    const float* rp = cb + (size_t)(r0 + r) * NN + c0; \
    f32x4 v0 = *(const f32x4*)rp; \
    f32x4 v1 = *(const f32x4*)(rp + 4); \
    float rowacc = 0.0f; \
    rowacc += fmaxf(v0[0] - thr, 0.0f) * (float)M##r.s0 * ys[c0 + 0]; \
    rowacc += fmaxf(v0[1] - thr, 0.0f) * (float)M##r.s1 * ys[c0 + 1]; \
    rowacc += fmaxf(v0[2] - thr, 0.0f) * (float)M##r.s2 * ys[c0 + 2]; \
    rowacc += fmaxf(v0[3] - thr, 0.0f) * (float)M##r.s3 * ys[c0 + 3]; \
    rowacc += fmaxf(v1[0] - thr, 0.0f) * (float)M##r.s4 * ys[c0 + 4]; \
    rowacc += fmaxf(v1[1] - thr, 0.0f) * (float)M##r.s5 * ys[c0 + 5]; \
    rowacc += fmaxf(v1[2] - thr, 0.0f) * (float)M##r.s6 * ys[c0 + 6]; \
    rowacc += fmaxf(v1[3] - thr, 0.0f) * (float)M##r.s7 * ys[c0 + 7]; \
    contrib += rowacc * xs[r0 + r]; }
  FOR16(FINP)
  #pragma unroll
  for (int m = 1; m < 64; m <<= 1) contrib += __shfl_xor(contrib, m, 64);
  if (lane == 0) wred[w] = contrib;
  __syncthreads();
  if (tid == 0) {
    float s2 = 0.0f;
    #pragma unroll
    for (int g = 0; g < 8; ++g) s2 += wred[g];
    gdist[blk] = s2;
  }
}

// ---------------- K5: deterministic finish: out = -mean_b(dist_b / m) ----------------
__global__ void k_final(const float* __restrict__ gdist, float* __restrict__ out) {
  int b = threadIdx.x & 63;
  float v = gdist[b] + gdist[b + 64] + gdist[b + 128] + gdist[b + 192];
  #pragma unroll
  for (int m = 1; m < 64; m <<= 1) v += __shfl_xor(v, m, 64);
  if (threadIdx.x == 0) out[0] = -v * (1.0f / (64.0f * 512.0f));
}

extern "C" void kernel_launch(void* const* d_in, const int* in_sizes, int n_in,
                              void* d_out, int out_size, void* d_ws, size_t ws_size,
                              hipStream_t stream) {
  const float* f1 = (const float*)d_in[0];
  const float* f2 = (const float*)d_in[1];
  char* ws = (char*)d_ws;
  __half* xn  = (__half*)(ws + 0);                 // 50,331,648 B (dead after k_gemm)
  __half* yn  = (__half*)(ws + 50331648);          // 50,331,648 B (dead after k_gemm)
  unsigned* gx = (unsigned*)(ws + 0);              // 15,728,640 B inbox, overlaps dead xn
  float* cosm = (float*)(ws + 100663296);          // 67,108,864 B
  int*   meta = (int*)(ws + 167772160);            // 2 ints
  float* gdist = (float*)(ws + 167772160 + 256);   // 256 floats

  k_init<<<1, 64, 0, stream>>>(meta);
  k_norm<<<16384, 256, 0, stream>>>(f1, f2, xn, yn);
  k_gemm<<<dim3(16, 64), 256, 0, stream>>>(xn, yn, cosm, meta);
  hipMemsetAsync(gx, 0, (size_t)30 * 64 * 4 * 512 * 4, stream);  // zero inbox (xn dead now)
  k_ipot<<<256, 512, 0, stream>>>(cosm, meta, gx, gdist);
  k_final<<<1, 64, 0, stream>>>(gdist, (float*)d_out);
}

// Round 8
// 243.328 us; speedup vs baseline: 1.0235x; 1.0235x over previous
//
#include <hip/hip_runtime.h>
#include <hip/hip_fp16.h>

#define NN 512
#define DD 768

typedef _Float16 half8 __attribute__((ext_vector_type(8)));
typedef _Float16 half4 __attribute__((ext_vector_type(4)));
typedef _Float16 half2v __attribute__((ext_vector_type(2)));
typedef float f32x4 __attribute__((ext_vector_type(4)));

__device__ __forceinline__ int f2ord(float f) {
  int i = __float_as_int(f);
  return i < 0 ? (i ^ 0x7fffffff) : i;
}
__device__ __forceinline__ float ord2f(int i) {
  return __int_as_float(i < 0 ? (i ^ 0x7fffffff) : i);
}

// async global->LDS, 16B per lane; LDS dest is wave-uniform base + lane*16 implicit
__device__ __forceinline__ void glds16(const void* g, void* l) {
  __builtin_amdgcn_global_load_lds((const __attribute__((address_space(1))) void*)g,
                                   (__attribute__((address_space(3))) void*)l, 16, 0, 0);
}

// ---------------- K0: init min/max meta + per-batch barrier counters ----------------
__global__ void k_init(int* meta, int* cnt) {
  int t = threadIdx.x;
  if (t == 0) {
    meta[0] = 0x7fffffff;  // ordered-int +max (min accumulator)
    meta[1] = 0x80000000;  // ordered-int -max (max accumulator)
  }
  if (t < 64) cnt[t * 16] = 0;  // 64B-strided per-batch counters (re-zeroed every launch)
}

// ---------------- K1: row-normalize + fp16 cast ----------------
__global__ __launch_bounds__(256) void k_norm(const float* __restrict__ f1,
                                              const float* __restrict__ f2,
                                              __half* __restrict__ xn,
                                              __half* __restrict__ yn) {
  int row = blockIdx.x * 4 + (threadIdx.x >> 6);
  int lane = threadIdx.x & 63;
  int r = row & 32767;
  const float* src = (row < 32768 ? f1 : f2) + (size_t)r * DD;
  __half* dst = (row < 32768 ? xn : yn) + (size_t)r * DD;
  f32x4 v0 = *(const f32x4*)(src + lane * 4);
  f32x4 v1 = *(const f32x4*)(src + lane * 4 + 256);
  f32x4 v2 = *(const f32x4*)(src + lane * 4 + 512);
  float s = v0[0]*v0[0] + v0[1]*v0[1] + v0[2]*v0[2] + v0[3]*v0[3]
          + v1[0]*v1[0] + v1[1]*v1[1] + v1[2]*v1[2] + v1[3]*v1[3]
          + v2[0]*v2[0] + v2[1]*v2[1] + v2[2]*v2[2] + v2[3]*v2[3];
  #pragma unroll
  for (int m = 1; m < 64; m <<= 1) s += __shfl_xor(s, m, 64);
  float f = 1.0f / (sqrtf(s) + 1e-12f);
  union U { __half2 h2[2]; uint2 u; };
  U u0, u1, u2;
  u0.h2[0] = __floats2half2_rn(v0[0]*f, v0[1]*f); u0.h2[1] = __floats2half2_rn(v0[2]*f, v0[3]*f);
  u1.h2[0] = __floats2half2_rn(v1[0]*f, v1[1]*f); u1.h2[1] = __floats2half2_rn(v1[2]*f, v1[3]*f);
  u2.h2[0] = __floats2half2_rn(v2[0]*f, v2[1]*f); u2.h2[1] = __floats2half2_rn(v2[2]*f, v2[3]*f);
  *(uint2*)(dst + lane * 4)       = u0.u;
  *(uint2*)(dst + lane * 4 + 256) = u1.u;
  *(uint2*)(dst + lane * 4 + 512) = u2.u;
}

// ---------------- K2: batched fp16 MFMA GEMM via global_load_lds double-buffer ----------
// cosm stored as FP16 (33 MB): halves GEMM write traffic + k_ipot INITAM read traffic.
// min/max still computed from fp32 accumulators (pre-rounding).
__global__ __launch_bounds__(256) void k_gemm(const __half* __restrict__ xn,
                                              const __half* __restrict__ yn,
                                              __half* __restrict__ cosm,
                                              int* __restrict__ meta) {
  __shared__ __align__(16) __half As[2][4096];  // [128][32] per buffer
  __shared__ __align__(16) __half Bs[2][4096];
  __shared__ float rmin[4], rmax[4];
  const int b  = blockIdx.y;
  const int ti = blockIdx.x >> 2;
  const int tj = blockIdx.x & 3;
  const int tid = threadIdx.x;
  const int wv = tid >> 6, lane = tid & 63;
  const int wr = (wv >> 1) * 64, wc = (wv & 1) * 64;
  const __half* Ab = xn + ((size_t)b * NN + (size_t)ti * 128) * DD;
  const __half* Bb = yn + ((size_t)b * NN + (size_t)tj * 128) * DD;
  const int srow = tid >> 2;
  const int scol = (tid & 3) * 8;
  const __half* ga0 = Ab + (size_t)srow * DD + scol;
  const __half* ga1 = ga0 + (size_t)64 * DD;
  const __half* gb0 = Bb + (size_t)srow * DD + scol;
  const __half* gb1 = gb0 + (size_t)64 * DD;
  f32x4 acc[4][4] = {};
  const int fr = lane & 15;
  const int kb = (lane >> 4) * 8;

#define STAGE(bf, kk) { \
    glds16(ga0 + (kk), &As[bf][wv * 512]); \
    glds16(ga1 + (kk), &As[bf][2048 + wv * 512]); \
    glds16(gb0 + (kk), &Bs[bf][wv * 512]); \
    glds16(gb1 + (kk), &Bs[bf][2048 + wv * 512]); }

  int buf = 0;
  STAGE(0, 0)
  for (int kk = 0; kk < DD; kk += 32) {
    __syncthreads();  // drains vmcnt: current slab resident
    if (kk + 32 < DD) STAGE(buf ^ 1, kk + 32)  // prefetch overlaps MFMA
    half8 af[4], bf4[4];
    #pragma unroll
    for (int g = 0; g < 4; ++g) {
      af[g]  = *(const half8*)(&As[buf][(wr + g * 16 + fr) * 32 + kb]);
      bf4[g] = *(const half8*)(&Bs[buf][(wc + g * 16 + fr) * 32 + kb]);
    }
    #pragma unroll
    for (int g = 0; g < 4; ++g) {
      #pragma unroll
      for (int h = 0; h < 4; ++h) {
        acc[g][h] = __builtin_amdgcn_mfma_f32_16x16x32_f16(af[g], bf4[h], acc[g][h], 0, 0, 0);
      }
    }
    buf ^= 1;
  }
  float vmin = 1e30f, vmax = -1e30f;
  __half* cb = cosm + (size_t)b * NN * NN;
  #pragma unroll
  for (int g = 0; g < 4; ++g) {
    #pragma unroll
    for (int h = 0; h < 4; ++h) {
      #pragma unroll
      for (int r2 = 0; r2 < 4; ++r2) {
        int row = ti * 128 + wr + g * 16 + (lane >> 4) * 4 + r2;
        int col = tj * 128 + wc + h * 16 + fr;
        float val = 1.0f - acc[g][h][r2];
        cb[(size_t)row * NN + col] = __float2half(val);
        vmin = fminf(vmin, val); vmax = fmaxf(vmax, val);
      }
    }
  }
  #pragma unroll
  for (int m = 1; m < 64; m <<= 1) {
    vmin = fminf(vmin, __shfl_xor(vmin, m, 64));
    vmax = fmaxf(vmax, __shfl_xor(vmax, m, 64));
  }
  if (lane == 0) { rmin[wv] = vmin; rmax[wv] = vmax; }
  __syncthreads();
  if (tid == 0) {
    float bm = fminf(fminf(rmin[0], rmin[1]), fminf(rmin[2], rmin[3]));
    float bx = fmaxf(fmaxf(rmax[0], rmax[1]), fmaxf(rmax[2], rmax[3]));
    atomicMin(meta + 0, f2ord(bm));
    atomicMax(meta + 1, f2ord(bx));
  }
}

// ---------------- K3: 30 IPOT iterations, 4 blocks/batch, A/M in NAMED half8 registers ----
// Round-6 counter-barrier exchange (measured best: RELAXED agent atomics, no fences;
// round-7 inbox-poll regressed from MALL poll traffic). FINP computes C' from the
// register-resident A via C' = -0.5*ln(A) -- no cosm re-read at the end.
#define FOR16(X) X(0) X(1) X(2) X(3) X(4) X(5) X(6) X(7) X(8) X(9) X(10) X(11) X(12) X(13) X(14) X(15)

#define AGLD(p) __hip_atomic_load((p), __ATOMIC_RELAXED, __HIP_MEMORY_SCOPE_AGENT)
#define AGST(p, v) __hip_atomic_store((p), (v), __ATOMIC_RELAXED, __HIP_MEMORY_SCOPE_AGENT)

__global__ __launch_bounds__(512, 2) void k_ipot(const __half* __restrict__ cosm,
                                                 const int* __restrict__ meta,
                                                 int* __restrict__ cnt,
                                                 float* __restrict__ gpart,
                                                 float* __restrict__ gdist) {
  __shared__ float xs[128];
  __shared__ float ys[NN];
  __shared__ __align__(16) _Float16 zs[NN];
  __shared__ __align__(16) _Float16 csh[8][520];
  __shared__ float wred[8];
  const int blk = blockIdx.x;
  const int b = blk & 63, qq = blk >> 6;  // partner blocks b, b+64, b+128, b+192
  const int tid = threadIdx.x;
  const int w = tid >> 6, lane = tid & 63;
  const int r0 = w * 16;
  const int c0 = lane * 8;
  const __half* cb = cosm + (size_t)b * NN * NN + (size_t)(qq * 128) * NN;
  const float gmn = ord2f(meta[0]);
  const float gmx = ord2f(meta[1]);
  const float thr = gmn + 0.1f * (gmx - gmn);

#define DECLAM(r) half8 A##r, M##r;
  FOR16(DECLAM)

#define INITAM(r) { \
    const __half* rp = cb + (size_t)(r0 + r) * NN + c0; \
    half8 hv = *(const half8*)rp; \
    A##r.s0 = (_Float16)__expf(-2.0f * fmaxf((float)hv.s0 - thr, 0.0f)); \
    A##r.s1 = (_Float16)__expf(-2.0f * fmaxf((float)hv.s1 - thr, 0.0f)); \
    A##r.s2 = (_Float16)__expf(-2.0f * fmaxf((float)hv.s2 - thr, 0.0f)); \
    A##r.s3 = (_Float16)__expf(-2.0f * fmaxf((float)hv.s3 - thr, 0.0f)); \
    A##r.s4 = (_Float16)__expf(-2.0f * fmaxf((float)hv.s4 - thr, 0.0f)); \
    A##r.s5 = (_Float16)__expf(-2.0f * fmaxf((float)hv.s5 - thr, 0.0f)); \
    A##r.s6 = (_Float16)__expf(-2.0f * fmaxf((float)hv.s6 - thr, 0.0f)); \
    A##r.s7 = (_Float16)__expf(-2.0f * fmaxf((float)hv.s7 - thr, 0.0f)); \
    M##r = A##r; }
  FOR16(INITAM)

  if (tid < 256) *(half2v*)(zs + 2 * tid) = (half2v){(_Float16)1.0f, (_Float16)1.0f};  // ẑ₁=1
  ys[tid] = 1.0f;  // ŷ₀=1
  __syncthreads();

  int* mycnt = cnt + b * 16;

  #pragma unroll 1
  for (int t = 1; t <= 30; ++t) {
    // ---- row pass: r_i = sum_j M_ij ẑ_j over own 8 cols; x̂ = 1/rowsum ----
    half8 zv = *(const half8*)(zs + c0);
    float rp16[16];
#define ROWP(r) { \
      half8 p = M##r * zv; \
      half4 q = p.lo + p.hi; \
      half2v q2 = q.lo + q.hi; \
      rp16[r] = (float)q2.x + (float)q2.y; }
    FOR16(ROWP)
    float c8[8];
    #pragma unroll
    for (int i = 0; i < 8; ++i) {
      float keep = (lane & 1) ? rp16[2*i+1] : rp16[2*i];
      float send = (lane & 1) ? rp16[2*i]   : rp16[2*i+1];
      c8[i] = keep + __shfl_xor(send, 1, 64);
    }
    float c4[4];
    #pragma unroll
    for (int i = 0; i < 4; ++i) {
      float keep = (lane & 2) ? c8[2*i+1] : c8[2*i];
      float send = (lane & 2) ? c8[2*i]   : c8[2*i+1];
      c4[i] = keep + __shfl_xor(send, 2, 64);
    }
    float d2[2];
    #pragma unroll
    for (int i = 0; i < 2; ++i) {
      float keep = (lane & 4) ? c4[2*i+1] : c4[2*i];
      float send = (lane & 4) ? c4[2*i]   : c4[2*i+1];
      d2[i] = keep + __shfl_xor(send, 4, 64);
    }
    float c1;
    {
      float keep = (lane & 8) ? d2[1] : d2[0];
      float send = (lane & 8) ? d2[0] : d2[1];
      c1 = keep + __shfl_xor(send, 8, 64);
    }
    c1 += __shfl_xor(c1, 16, 64);
    c1 += __shfl_xor(c1, 32, 64);
    if (lane < 16) xs[r0 + lane] = 1.0f / c1;  // wave-local write; same-wave reads below
    // ---- col pass: cac_j = sum over own 16 rows of M*x̂ (xs wave-local) ----
    half8 cac = (half8)(_Float16)0.0f;
#define COLP(r) { _Float16 xh = (_Float16)xs[r0 + r]; cac += M##r * xh; }
    FOR16(COLP)
    *(half8*)(&csh[w][c0]) = cac;
#define UPDM(r) M##r *= A##r;
    if (t < 30) { FOR16(UPDM) }  // M <- M∘A in regs, overlaps LDS latency
    __syncthreads();
    // ---- block col-reduce -> RELAXED agent stores (double-buffered gpart) ----
    float* gp = gpart + ((size_t)((t & 1) * 256 + blk) * 512);
    if (tid < 256) {
      float a0 = 0.0f, a1 = 0.0f;
      #pragma unroll
      for (int g = 0; g < 8; ++g) {
        half2v pv = *(const half2v*)(&csh[g][2 * tid]);
        a0 += (float)pv.x; a1 += (float)pv.y;
      }
      AGST(gp + tid * 2,     a0);
      AGST(gp + tid * 2 + 1, a1);
    }
    __syncthreads();  // s_waitcnt vmcnt(0) before s_barrier: stores at coherent point
    // ---- 4-block barrier: monotonic counter, RELAXED only ----
    if (tid == 0) {
      __hip_atomic_fetch_add(mycnt, 1, __ATOMIC_RELAXED, __HIP_MEMORY_SCOPE_AGENT);
      while (__hip_atomic_load(mycnt, __ATOMIC_RELAXED, __HIP_MEMORY_SCOPE_AGENT) < 4 * t)
        __builtin_amdgcn_s_sleep(1);
    }
    __syncthreads();
    // ---- read 4 partners' partials, replicated ŷ/ẑ update ----
    if (tid < 256) {
      float a0 = 0.0f, a1 = 0.0f;
      #pragma unroll
      for (int q2 = 0; q2 < 4; ++q2) {
        const float* gpb = gpart + ((size_t)((t & 1) * 256 + b + 64 * q2) * 512);
        a0 += AGLD(gpb + tid * 2);
        a1 += AGLD(gpb + tid * 2 + 1);
      }
      float yo0 = ys[2 * tid], yo1 = ys[2 * tid + 1];
      float y0 = 1.0f / a0;
      float y1 = 1.0f / a1;
      *(half2v*)(zs + 2 * tid) = (half2v){(_Float16)(y0 * y0 / yo0), (_Float16)(y1 * y1 / yo1)};
      ys[2 * tid] = y0; ys[2 * tid + 1] = y1;
    }
    __syncthreads();
  }

  // ---- dist partial = sum_ij C'_ij * M_ij * x̂_i * ŷ_j, C' = -0.5 ln(A) from regs ----
  // (A==1.0 exactly for below-threshold elems -> C'=0 exactly; A >= e^-4 -> log safe)
  float contrib = 0.0f;
#define FINP(r) { \
    float rowacc = 0.0f; \
    rowacc += -0.34657359f * __log2f((float)A##r.s0) * (float)M##r.s0 * ys[c0 + 0]; \
    rowacc += -0.34657359f * __log2f((float)A##r.s1) * (float)M##r.s1 * ys[c0 + 1]; \
    rowacc += -0.34657359f * __log2f((float)A##r.s2) * (float)M##r.s2 * ys[c0 + 2]; \
    rowacc += -0.34657359f * __log2f((float)A##r.s3) * (float)M##r.s3 * ys[c0 + 3]; \
    rowacc += -0.34657359f * __log2f((float)A##r.s4) * (float)M##r.s4 * ys[c0 + 4]; \
    rowacc += -0.34657359f * __log2f((float)A##r.s5) * (float)M##r.s5 * ys[c0 + 5]; \
    rowacc += -0.34657359f * __log2f((float)A##r.s6) * (float)M##r.s6 * ys[c0 + 6]; \
    rowacc += -0.34657359f * __log2f((float)A##r.s7) * (float)M##r.s7 * ys[c0 + 7]; \
    contrib += rowacc * xs[r0 + r]; }
  FOR16(FINP)
  #pragma unroll
  for (int m = 1; m < 64; m <<= 1) contrib += __shfl_xor(contrib, m, 64);
  if (lane == 0) wred[w] = contrib;
  __syncthreads();
  if (tid == 0) {
    float s2 = 0.0f;
    #pragma unroll
    for (int g = 0; g < 8; ++g) s2 += wred[g];
    gdist[blk] = s2;
  }
}

// ---------------- K5: deterministic finish: out = -mean_b(dist_b / m) ----------------
__global__ void k_final(const float* __restrict__ gdist, float* __restrict__ out) {
  int b = threadIdx.x & 63;
  float v = gdist[b] + gdist[b + 64] + gdist[b + 128] + gdist[b + 192];
  #pragma unroll
  for (int m = 1; m < 64; m <<= 1) v += __shfl_xor(v, m, 64);
  if (threadIdx.x == 0) out[0] = -v * (1.0f / (64.0f * 512.0f));
}

extern "C" void kernel_launch(void* const* d_in, const int* in_sizes, int n_in,
                              void* d_out, int out_size, void* d_ws, size_t ws_size,
                              hipStream_t stream) {
  const float* f1 = (const float*)d_in[0];
  const float* f2 = (const float*)d_in[1];
  char* ws = (char*)d_ws;
  __half* xn  = (__half*)(ws + 0);                 // 50,331,648 B
  __half* yn  = (__half*)(ws + 50331648);          // 50,331,648 B (dead after k_gemm)
  float* gpart = (float*)(ws + 50331648);          // 1 MB, overlaps yn (k_ipot only)
  __half* cosm = (__half*)(ws + 100663296);        // 33,554,432 B (fp16 now)
  int*   meta = (int*)(ws + 167772160);            // 2 ints
  int*   cnt  = (int*)(ws + 167772160 + 256);      // 64 x 16 ints
  float* gdist = (float*)(ws + 167772160 + 256 + 4096);  // 256 floats

  k_init<<<1, 64, 0, stream>>>(meta, cnt);
  k_norm<<<16384, 256, 0, stream>>>(f1, f2, xn, yn);
  k_gemm<<<dim3(16, 64), 256, 0, stream>>>(xn, yn, cosm, meta);
  k_ipot<<<256, 512, 0, stream>>>(cosm, meta, cnt, gpart, gdist);
  k_final<<<1, 64, 0, stream>>>(gdist, (float*)d_out);
}

// Round 11
// 227.048 us; speedup vs baseline: 1.0969x; 1.0717x over previous
//
#include <hip/hip_runtime.h>
#include <hip/hip_fp16.h>

#define NN 512
#define DD 768

typedef _Float16 half8 __attribute__((ext_vector_type(8)));
typedef _Float16 half4 __attribute__((ext_vector_type(4)));
typedef _Float16 half2v __attribute__((ext_vector_type(2)));
typedef float f32x4 __attribute__((ext_vector_type(4)));

__device__ __forceinline__ int f2ord(float f) {
  int i = __float_as_int(f);
  return i < 0 ? (i ^ 0x7fffffff) : i;
}
__device__ __forceinline__ float ord2f(int i) {
  return __int_as_float(i < 0 ? (i ^ 0x7fffffff) : i);
}

// async global->LDS, 16B per lane; LDS dest = wave-uniform base + lane*16 implicit
__device__ __forceinline__ void glds16(const void* g, void* l) {
  __builtin_amdgcn_global_load_lds((const __attribute__((address_space(1))) void*)g,
                                   (__attribute__((address_space(3))) void*)l, 16, 0, 0);
}

// ---------------- K0: init meta + counters ----------------
__global__ void k_init(int* meta, int* cnt) {
  int t = threadIdx.x;
  if (t == 0) {
    meta[0] = 0x7fffffff;
    meta[1] = 0x80000000;
    cnt[1024] = 0;            // global 256-block barrier counter
  }
  if (t < 64) cnt[t * 16] = 0;  // per-batch counters
}

// ---------------- K1: row-normalize + fp16 cast ----------------
__global__ __launch_bounds__(256) void k_norm(const float* __restrict__ f1,
                                              const float* __restrict__ f2,
                                              __half* __restrict__ xn,
                                              __half* __restrict__ yn) {
  int row = blockIdx.x * 4 + (threadIdx.x >> 6);
  int lane = threadIdx.x & 63;
  int r = row & 32767;
  const float* src = (row < 32768 ? f1 : f2) + (size_t)r * DD;
  __half* dst = (row < 32768 ? xn : yn) + (size_t)r * DD;
  f32x4 v0 = *(const f32x4*)(src + lane * 4);
  f32x4 v1 = *(const f32x4*)(src + lane * 4 + 256);
  f32x4 v2 = *(const f32x4*)(src + lane * 4 + 512);
  float s = v0[0]*v0[0] + v0[1]*v0[1] + v0[2]*v0[2] + v0[3]*v0[3]
          + v1[0]*v1[0] + v1[1]*v1[1] + v1[2]*v1[2] + v1[3]*v1[3]
          + v2[0]*v2[0] + v2[1]*v2[1] + v2[2]*v2[2] + v2[3]*v2[3];
  #pragma unroll
  for (int m = 1; m < 64; m <<= 1) s += __shfl_xor(s, m, 64);
  float f = 1.0f / (sqrtf(s) + 1e-12f);
  union U { __half2 h2[2]; uint2 u; };
  U u0, u1, u2;
  u0.h2[0] = __floats2half2_rn(v0[0]*f, v0[1]*f); u0.h2[1] = __floats2half2_rn(v0[2]*f, v0[3]*f);
  u1.h2[0] = __floats2half2_rn(v1[0]*f, v1[1]*f); u1.h2[1] = __floats2half2_rn(v1[2]*f, v1[3]*f);
  u2.h2[0] = __floats2half2_rn(v2[0]*f, v2[1]*f); u2.h2[1] = __floats2half2_rn(v2[2]*f, v2[3]*f);
  *(uint2*)(dst + lane * 4)       = u0.u;
  *(uint2*)(dst + lane * 4 + 256) = u1.u;
  *(uint2*)(dst + lane * 4 + 512) = u2.u;
}

// ---------------- K2: FUSED gemm + threshold + 30-iteration IPOT ----------------
// 256 blocks, 512 threads. Block (b=blk&63, qq=blk>>6) owns rows [qq*128,+128) of
// batch b (all 4 partners on one XCD). Wave sv owns rows 16sv (GEMM output AND ipot).
// Phases: MFMA GEMM (C in regs) -> global minmax barrier -> A=exp(-2relu(C-thr))
// -> intra-wave LDS relayout -> 30 ipot iterations (proven r6/r8 exchange) -> FINP.
#define FOR16(X) X(0) X(1) X(2) X(3) X(4) X(5) X(6) X(7) X(8) X(9) X(10) X(11) X(12) X(13) X(14) X(15)

#define AGLD(p) __hip_atomic_load((p), __ATOMIC_RELAXED, __HIP_MEMORY_SCOPE_AGENT)
#define AGST(p, v) __hip_atomic_store((p), (v), __ATOMIC_RELAXED, __HIP_MEMORY_SCOPE_AGENT)

struct IpotLds {
  float xs[128];
  float ys[NN];
  _Float16 zs[NN];
  _Float16 csh[8][520];
  float wred[8];
};
union MainLds {
  _Float16 Bs[2][16384];   // 64KB: GEMM B staging [2 buf][kgroup g][row][8 halfs]
  _Float16 At[4][8192];    // 64KB: transpose regions (16KB per wave-slot)
  float mm[16];            // local minmax scratch
  int mmi[16];             // global minmax scratch
  IpotLds ip;              // ~12KB ipot state
};

__global__ __launch_bounds__(512, 2) void k_main(const __half* __restrict__ xn,
                                                 const __half* __restrict__ yn,
                                                 int* __restrict__ meta,
                                                 int* __restrict__ cnt,
                                                 int* __restrict__ gmm,
                                                 float* __restrict__ gpart,
                                                 float* __restrict__ gdist) {
  __shared__ __align__(16) MainLds u;
  const int blk = blockIdx.x;
  const int b = blk & 63, qq = blk >> 6;
  const int tid = threadIdx.x;
  const int sv = tid >> 6, lane = tid & 63;
  const int fr = lane & 15;
  const int g8 = (lane >> 4) * 8;     // k-offset in halfs
  const int r0 = sv * 16;
  const int c0 = lane * 8;
  const __half* xnb = xn + ((size_t)b * NN + qq * 128 + sv * 16) * DD;  // wave's 16 rows
  const __half* ynb = yn + (size_t)b * NN * DD;

  // ================= GEMM: acc[c] = C-tile rows 16sv.., cols 16c.. =================
  f32x4 acc[32] = {};
#define STAGE(bf, kk) { \
    const __half* ys_ = ynb + (size_t)(sv * 64 + lane) * DD + (kk); \
    glds16(ys_ +  0, (char*)u.Bs[bf] +     sv * 1024); \
    glds16(ys_ +  8, (char*)u.Bs[bf] +  8192 + sv * 1024); \
    glds16(ys_ + 16, (char*)u.Bs[bf] + 16384 + sv * 1024); \
    glds16(ys_ + 24, (char*)u.Bs[bf] + 24576 + sv * 1024); }
  int buf = 0;
  STAGE(0, 0)
  half8 afp = *(const half8*)(xnb + (size_t)fr * DD + g8);
  for (int kk = 0; kk < DD; kk += 32) {
    __syncthreads();                       // drains vmcnt: Bs[buf] resident
    if (kk + 32 < DD) STAGE(buf ^ 1, kk + 32)
    half8 afc = afp;
    if (kk + 32 < DD) afp = *(const half8*)(xnb + (size_t)fr * DD + (kk + 32) + g8);
    #pragma unroll
    for (int c = 0; c < 32; ++c) {
      half8 bf = *(const half8*)(&u.Bs[buf][(lane >> 4) * 4096 + (16 * c + fr) * 8]);
      acc[c] = __builtin_amdgcn_mfma_f32_16x16x32_f16(afc, bf, acc[c], 0, 0, 0);
    }
    buf ^= 1;
  }

  // ================= global min/max -> thr (proven barrier pattern) =================
  float vmin = 1e30f, vmax = -1e30f;
  #pragma unroll
  for (int c = 0; c < 32; ++c) {
    #pragma unroll
    for (int r2 = 0; r2 < 4; ++r2) {
      float val = 1.0f - acc[c][r2];
      vmin = fminf(vmin, val); vmax = fmaxf(vmax, val);
    }
  }
  #pragma unroll
  for (int m = 1; m < 64; m <<= 1) {
    vmin = fminf(vmin, __shfl_xor(vmin, m, 64));
    vmax = fmaxf(vmax, __shfl_xor(vmax, m, 64));
  }
  __syncthreads();                          // Bs dead; union repurposed
  if (lane == 0) { u.mm[sv] = vmin; u.mm[8 + sv] = vmax; }
  __syncthreads();
  if (tid == 0) {
    float bm = u.mm[0], bx = u.mm[8];
    #pragma unroll
    for (int g = 1; g < 8; ++g) { bm = fminf(bm, u.mm[g]); bx = fmaxf(bx, u.mm[8 + g]); }
    AGST(gmm + blk, f2ord(bm));
    AGST(gmm + 256 + blk, f2ord(bx));
  }
  __syncthreads();                          // tid0's stores drained at its barrier arrival
  if (tid == 0) {
    int* cnt2 = cnt + 1024;
    __hip_atomic_fetch_add(cnt2, 1, __ATOMIC_RELAXED, __HIP_MEMORY_SCOPE_AGENT);
    while (AGLD(cnt2) < 256) __builtin_amdgcn_s_sleep(1);
  }
  __syncthreads();
  {
    int mo = AGLD(gmm + tid);               // tid<256: min-ords; tid>=256: max-ords
    #pragma unroll
    for (int m = 1; m < 64; m <<= 1) {
      int o = __shfl_xor(mo, m, 64);
      mo = (sv < 4) ? (mo < o ? mo : o) : (mo > o ? mo : o);
    }
    if (lane == 0) u.mmi[sv] = mo;
  }
  __syncthreads();
  int gmnord = u.mmi[0], gmxord = u.mmi[4];
  #pragma unroll
  for (int g = 1; g < 4; ++g) {
    gmnord = gmnord < u.mmi[g] ? gmnord : u.mmi[g];
    gmxord = gmxord > u.mmi[4 + g] ? gmxord : u.mmi[4 + g];
  }
  const float gmn = ord2f(gmnord);
  const float gmx = ord2f(gmxord);
  const float thr = gmn + 0.1f * (gmx - gmn);

  // ================= A = exp(-2 relu(C-thr)); intra-wave relayout via LDS ==========
#define DECLAM(r) half8 A##r, M##r;
  FOR16(DECLAM)

  // write MFMA-layout A into swizzled region; q=(row>>2)&3 == lane>>4
#define TWRITE { \
    _Float16* reg_ = u.At[sv & 3]; \
    const int q_ = lane >> 4; \
    _Pragma("unroll") \
    for (int c = 0; c < 32; ++c) { \
      _Pragma("unroll") \
      for (int r2 = 0; r2 < 4; ++r2) { \
        float val_ = 1.0f - acc[c][r2]; \
        float a_ = __expf(-2.0f * fmaxf(val_ - thr, 0.0f)); \
        int off_ = (((4 * q_ + r2) * 1024 + (16 * c + fr) * 2) ^ (q_ << 4)) >> 1; \
        reg_[off_] = (_Float16)a_; \
      } \
    } }

#define TREAD(r) { \
    A##r = *(const half8*)((const char*)u.At[sv & 3] + \
            (((r) * 1024 + lane * 16) ^ ((((r) >> 2) & 3) << 4))); \
    M##r = A##r; }

  __syncthreads();
  if (sv < 4) TWRITE
  __syncthreads();
  if (sv < 4) { FOR16(TREAD) }
  __syncthreads();
  if (sv >= 4) TWRITE
  __syncthreads();
  if (sv >= 4) { FOR16(TREAD) }
  __syncthreads();

  // ================= ipot state init =================
  if (tid < 256) *(half2v*)(u.ip.zs + 2 * tid) = (half2v){(_Float16)1.0f, (_Float16)1.0f};
  u.ip.ys[tid] = 1.0f;
  __syncthreads();

  int* mycnt = cnt + b * 16;

  // ================= 30 iterations (verbatim r6/r8 proven) =================
  #pragma unroll 1
  for (int t = 1; t <= 30; ++t) {
    half8 zv = *(const half8*)(u.ip.zs + c0);
    float rp16[16];
#define ROWP(r) { \
      half8 p = M##r * zv; \
      half4 q = p.lo + p.hi; \
      half2v q2 = q.lo + q.hi; \
      rp16[r] = (float)q2.x + (float)q2.y; }
    FOR16(ROWP)
    float c8[8];
    #pragma unroll
    for (int i = 0; i < 8; ++i) {
      float keep = (lane & 1) ? rp16[2*i+1] : rp16[2*i];
      float send = (lane & 1) ? rp16[2*i]   : rp16[2*i+1];
      c8[i] = keep + __shfl_xor(send, 1, 64);
    }
    float c4[4];
    #pragma unroll
    for (int i = 0; i < 4; ++i) {
      float keep = (lane & 2) ? c8[2*i+1] : c8[2*i];
      float send = (lane & 2) ? c8[2*i]   : c8[2*i+1];
      c4[i] = keep + __shfl_xor(send, 2, 64);
    }
    float d2[2];
    #pragma unroll
    for (int i = 0; i < 2; ++i) {
      float keep = (lane & 4) ? c4[2*i+1] : c4[2*i];
      float send = (lane & 4) ? c4[2*i]   : c4[2*i+1];
      d2[i] = keep + __shfl_xor(send, 4, 64);
    }
    float c1;
    {
      float keep = (lane & 8) ? d2[1] : d2[0];
      float send = (lane & 8) ? d2[0] : d2[1];
      c1 = keep + __shfl_xor(send, 8, 64);
    }
    c1 += __shfl_xor(c1, 16, 64);
    c1 += __shfl_xor(c1, 32, 64);
    if (lane < 16) u.ip.xs[r0 + lane] = 1.0f / c1;
    half8 cac = (half8)(_Float16)0.0f;
#define COLP(r) { _Float16 xh = (_Float16)u.ip.xs[r0 + r]; cac += M##r * xh; }
    FOR16(COLP)
    *(half8*)(&u.ip.csh[sv][c0]) = cac;
#define UPDM(r) M##r *= A##r;
    if (t < 30) { FOR16(UPDM) }
    __syncthreads();
    float* gp = gpart + ((size_t)((t & 1) * 256 + blk) * 512);
    if (tid < 256) {
      float a0 = 0.0f, a1 = 0.0f;
      #pragma unroll
      for (int g = 0; g < 8; ++g) {
        half2v pv = *(const half2v*)(&u.ip.csh[g][2 * tid]);
        a0 += (float)pv.x; a1 += (float)pv.y;
      }
      AGST(gp + tid * 2,     a0);
      AGST(gp + tid * 2 + 1, a1);
    }
    __syncthreads();
    if (tid == 0) {
      __hip_atomic_fetch_add(mycnt, 1, __ATOMIC_RELAXED, __HIP_MEMORY_SCOPE_AGENT);
      while (__hip_atomic_load(mycnt, __ATOMIC_RELAXED, __HIP_MEMORY_SCOPE_AGENT) < 4 * t)
        __builtin_amdgcn_s_sleep(1);
    }
    __syncthreads();
    if (tid < 256) {
      float a0 = 0.0f, a1 = 0.0f;
      #pragma unroll
      for (int q2 = 0; q2 < 4; ++q2) {
        const float* gpb = gpart + ((size_t)((t & 1) * 256 + b + 64 * q2) * 512);
        a0 += AGLD(gpb + tid * 2);
        a1 += AGLD(gpb + tid * 2 + 1);
      }
      float yo0 = u.ip.ys[2 * tid], yo1 = u.ip.ys[2 * tid + 1];
      float y0 = 1.0f / a0;
      float y1 = 1.0f / a1;
      *(half2v*)(u.ip.zs + 2 * tid) = (half2v){(_Float16)(y0 * y0 / yo0), (_Float16)(y1 * y1 / yo1)};
      u.ip.ys[2 * tid] = y0; u.ip.ys[2 * tid + 1] = y1;
    }
    __syncthreads();
  }

  // ================= dist partial: C' = -0.5 ln A (regs) =================
  float contrib = 0.0f;
#define FINP(r) { \
    float rowacc = 0.0f; \
    rowacc += -0.34657359f * __log2f((float)A##r.s0) * (float)M##r.s0 * u.ip.ys[c0 + 0]; \
    rowacc += -0.34657359f * __log2f((float)A##r.s1) * (float)M##r.s1 * u.ip.ys[c0 + 1]; \
    rowacc += -0.34657359f * __log2f((float)A##r.s2) * (float)M##r.s2 * u.ip.ys[c0 + 2]; \
    rowacc += -0.34657359f * __log2f((float)A##r.s3) * (float)M##r.s3 * u.ip.ys[c0 + 3]; \
    rowacc += -0.34657359f * __log2f((float)A##r.s4) * (float)M##r.s4 * u.ip.ys[c0 + 4]; \
    rowacc += -0.34657359f * __log2f((float)A##r.s5) * (float)M##r.s5 * u.ip.ys[c0 + 5]; \
    rowacc += -0.34657359f * __log2f((float)A##r.s6) * (float)M##r.s6 * u.ip.ys[c0 + 6]; \
    rowacc += -0.34657359f * __log2f((float)A##r.s7) * (float)M##r.s7 * u.ip.ys[c0 + 7]; \
    contrib += rowacc * u.ip.xs[r0 + r]; }
  FOR16(FINP)
  #pragma unroll
  for (int m = 1; m < 64; m <<= 1) contrib += __shfl_xor(contrib, m, 64);
  if (lane == 0) u.ip.wred[sv] = contrib;
  __syncthreads();
  if (tid == 0) {
    float s2 = 0.0f;
    #pragma unroll
    for (int g = 0; g < 8; ++g) s2 += u.ip.wred[g];
    gdist[blk] = s2;
  }
}

// ---------------- K5: deterministic finish: out = -mean_b(dist_b / m) ----------------
__global__ void k_final(const float* __restrict__ gdist, float* __restrict__ out) {
  int b = threadIdx.x & 63;
  float v = gdist[b] + gdist[b + 64] + gdist[b + 128] + gdist[b + 192];
  #pragma unroll
  for (int m = 1; m < 64; m <<= 1) v += __shfl_xor(v, m, 64);
  if (threadIdx.x == 0) out[0] = -v * (1.0f / (64.0f * 512.0f));
}

extern "C" void kernel_launch(void* const* d_in, const int* in_sizes, int n_in,
                              void* d_out, int out_size, void* d_ws, size_t ws_size,
                              hipStream_t stream) {
  const float* f1 = (const float*)d_in[0];
  const float* f2 = (const float*)d_in[1];
  char* ws = (char*)d_ws;
  __half* xn   = (__half*)(ws + 0);                  // 50,331,648 B (live through k_main GEMM)
  __half* yn   = (__half*)(ws + 50331648);           // 50,331,648 B (live through k_main GEMM)
  float* gpart = (float*)(ws + 100663296);           // 1 MB (old cosm region; used post-GEMM)
  int*   meta  = (int*)(ws + 167772160);             // 2 ints
  int*   cnt   = (int*)(ws + 167772160 + 256);       // per-batch cnts + cnt[1024] global
  int*   gmm   = (int*)(ws + 167772160 + 256 + 8192);// 512 ints block min/max
  float* gdist = (float*)(ws + 167772160 + 256 + 8192 + 2048);  // 256 floats

  k_init<<<1, 64, 0, stream>>>(meta, cnt);
  k_norm<<<16384, 256, 0, stream>>>(f1, f2, xn, yn);
  k_main<<<256, 512, 0, stream>>>(xn, yn, meta, cnt, gmm, gpart, gdist);
  k_final<<<1, 64, 0, stream>>>(gdist, (float*)d_out);
}

// Round 12
// 196.580 us; speedup vs baseline: 1.2669x; 1.1550x over previous
//
#include <hip/hip_runtime.h>
#include <hip/hip_fp16.h>

#define NN 512
#define DD 768

typedef _Float16 half8 __attribute__((ext_vector_type(8)));
typedef _Float16 half4 __attribute__((ext_vector_type(4)));
typedef _Float16 half2v __attribute__((ext_vector_type(2)));
typedef float f32x4 __attribute__((ext_vector_type(4)));

__device__ __forceinline__ int f2ord(float f) {
  int i = __float_as_int(f);
  return i < 0 ? (i ^ 0x7fffffff) : i;
}
__device__ __forceinline__ float ord2f(int i) {
  return __int_as_float(i < 0 ? (i ^ 0x7fffffff) : i);
}

// async global->LDS, 16B per lane; LDS dest = wave-uniform base + lane*16 implicit
__device__ __forceinline__ void glds16(const void* g, void* l) {
  __builtin_amdgcn_global_load_lds((const __attribute__((address_space(1))) void*)g,
                                   (__attribute__((address_space(3))) void*)l, 16, 0, 0);
}

// ---------------- K0: init meta + counters ----------------
__global__ void k_init(int* meta, int* cnt) {
  int t = threadIdx.x;
  if (t == 0) {
    meta[0] = 0x7fffffff;
    meta[1] = 0x80000000;
    cnt[1024] = 0;            // global 256-block barrier counter
  }
  if (t < 64) cnt[t * 16] = 0;  // per-batch counters
}

// ---------------- K1: row-normalize + fp16 cast ----------------
__global__ __launch_bounds__(256) void k_norm(const float* __restrict__ f1,
                                              const float* __restrict__ f2,
                                              __half* __restrict__ xn,
                                              __half* __restrict__ yn) {
  int row = blockIdx.x * 4 + (threadIdx.x >> 6);
  int lane = threadIdx.x & 63;
  int r = row & 32767;
  const float* src = (row < 32768 ? f1 : f2) + (size_t)r * DD;
  __half* dst = (row < 32768 ? xn : yn) + (size_t)r * DD;
  f32x4 v0 = *(const f32x4*)(src + lane * 4);
  f32x4 v1 = *(const f32x4*)(src + lane * 4 + 256);
  f32x4 v2 = *(const f32x4*)(src + lane * 4 + 512);
  float s = v0[0]*v0[0] + v0[1]*v0[1] + v0[2]*v0[2] + v0[3]*v0[3]
          + v1[0]*v1[0] + v1[1]*v1[1] + v1[2]*v1[2] + v1[3]*v1[3]
          + v2[0]*v2[0] + v2[1]*v2[1] + v2[2]*v2[2] + v2[3]*v2[3];
  #pragma unroll
  for (int m = 1; m < 64; m <<= 1) s += __shfl_xor(s, m, 64);
  float f = 1.0f / (sqrtf(s) + 1e-12f);
  union U { __half2 h2[2]; uint2 u; };
  U u0, u1, u2;
  u0.h2[0] = __floats2half2_rn(v0[0]*f, v0[1]*f); u0.h2[1] = __floats2half2_rn(v0[2]*f, v0[3]*f);
  u1.h2[0] = __floats2half2_rn(v1[0]*f, v1[1]*f); u1.h2[1] = __floats2half2_rn(v1[2]*f, v1[3]*f);
  u2.h2[0] = __floats2half2_rn(v2[0]*f, v2[1]*f); u2.h2[1] = __floats2half2_rn(v2[2]*f, v2[3]*f);
  *(uint2*)(dst + lane * 4)       = u0.u;
  *(uint2*)(dst + lane * 4 + 256) = u1.u;
  *(uint2*)(dst + lane * 4 + 512) = u2.u;
}

// ---------------- K2: FUSED gemm + threshold + 30-iteration IPOT ----------------
// 256 blocks, 512 threads. Block (b=blk&63, qq=blk>>6) owns rows [qq*128,+128) of
// batch b. Wave sv owns rows 16sv (GEMM output AND ipot). B-LDS layout is r8's
// proven conflict-free [row][4 kgroups x 8 halfs] (row stride 64B), staged with
// per-lane-permuted global source (glds dest stays linear). Exchange partials fp16.
#define FOR16(X) X(0) X(1) X(2) X(3) X(4) X(5) X(6) X(7) X(8) X(9) X(10) X(11) X(12) X(13) X(14) X(15)

#define AGLD(p) __hip_atomic_load((p), __ATOMIC_RELAXED, __HIP_MEMORY_SCOPE_AGENT)
#define AGST(p, v) __hip_atomic_store((p), (v), __ATOMIC_RELAXED, __HIP_MEMORY_SCOPE_AGENT)

struct IpotLds {
  float xs[128];
  float ys[NN];
  _Float16 zs[NN];
  _Float16 csh[8][520];
  float wred[8];
};
union MainLds {
  _Float16 Bs[2][16384];   // 64KB: [buf][row 0..511][32 halfs] row stride 64B
  _Float16 At[4][8192];    // 64KB: transpose regions (16KB per wave-slot)
  float mm[16];
  int mmi[16];
  IpotLds ip;
};

__global__ __launch_bounds__(512, 2) void k_main(const __half* __restrict__ xn,
                                                 const __half* __restrict__ yn,
                                                 int* __restrict__ meta,
                                                 int* __restrict__ cnt,
                                                 int* __restrict__ gmm,
                                                 unsigned* __restrict__ gpart,
                                                 float* __restrict__ gdist) {
  __shared__ __align__(16) MainLds u;
  const int blk = blockIdx.x;
  const int b = blk & 63, qq = blk >> 6;
  const int tid = threadIdx.x;
  const int sv = tid >> 6, lane = tid & 63;
  const int fr = lane & 15;
  const int g8 = (lane >> 4) * 8;     // k-offset in halfs
  const int r0 = sv * 16;
  const int c0 = lane * 8;
  const __half* xnb = xn + ((size_t)b * NN + qq * 128 + sv * 16) * DD;  // wave's 16 rows
  const __half* ynb = yn + (size_t)b * NN * DD;

  // ================= GEMM: acc[c] = C-tile rows 16sv.., cols 16c.. =================
  f32x4 acc[32] = {};
  // stage rows 128j + sv*16 + (lane>>2), k-chunk (lane&3): lands at [row][kgroup]
  // byte (128j + sv*16 + lane>>2)*64 + (lane&3)*16 == region base + lane*16 (linear ✓)
#define STAGE(bf, kk) { \
    _Pragma("unroll") \
    for (int j = 0; j < 4; ++j) { \
      const __half* ys_ = ynb + (size_t)(128 * j + sv * 16 + (lane >> 2)) * DD + (kk) + (lane & 3) * 8; \
      glds16(ys_, (char*)u.Bs[bf] + j * 8192 + sv * 1024); \
    } }
  int buf = 0;
  STAGE(0, 0)
  half8 afp = *(const half8*)(xnb + (size_t)fr * DD + g8);
  for (int kk = 0; kk < DD; kk += 32) {
    __syncthreads();                       // drains vmcnt: Bs[buf] resident
    if (kk + 32 < DD) STAGE(buf ^ 1, kk + 32)
    half8 afc = afp;
    if (kk + 32 < DD) afp = *(const half8*)(xnb + (size_t)fr * DD + (kk + 32) + g8);
    #pragma unroll
    for (int c = 0; c < 32; ++c) {
      half8 bf = *(const half8*)(&u.Bs[buf][(16 * c + fr) * 32 + g8]);  // r8 layout
      acc[c] = __builtin_amdgcn_mfma_f32_16x16x32_f16(afc, bf, acc[c], 0, 0, 0);
    }
    buf ^= 1;
  }

  // ================= global min/max -> thr (proven barrier pattern) =================
  float vmin = 1e30f, vmax = -1e30f;
  #pragma unroll
  for (int c = 0; c < 32; ++c) {
    #pragma unroll
    for (int r2 = 0; r2 < 4; ++r2) {
      float val = 1.0f - acc[c][r2];
      vmin = fminf(vmin, val); vmax = fmaxf(vmax, val);
    }
  }
  #pragma unroll
  for (int m = 1; m < 64; m <<= 1) {
    vmin = fminf(vmin, __shfl_xor(vmin, m, 64));
    vmax = fmaxf(vmax, __shfl_xor(vmax, m, 64));
  }
  __syncthreads();                          // Bs dead; union repurposed
  if (lane == 0) { u.mm[sv] = vmin; u.mm[8 + sv] = vmax; }
  __syncthreads();
  if (tid == 0) {
    float bm = u.mm[0], bx = u.mm[8];
    #pragma unroll
    for (int g = 1; g < 8; ++g) { bm = fminf(bm, u.mm[g]); bx = fmaxf(bx, u.mm[8 + g]); }
    AGST(gmm + blk, (unsigned)f2ord(bm));
    AGST(gmm + 256 + blk, (unsigned)f2ord(bx));
  }
  __syncthreads();                          // tid0's stores drained at its barrier arrival
  if (tid == 0) {
    int* cnt2 = cnt + 1024;
    __hip_atomic_fetch_add(cnt2, 1, __ATOMIC_RELAXED, __HIP_MEMORY_SCOPE_AGENT);
    while (__hip_atomic_load(cnt2, __ATOMIC_RELAXED, __HIP_MEMORY_SCOPE_AGENT) < 256)
      __builtin_amdgcn_s_sleep(1);
  }
  __syncthreads();
  {
    int mo = (int)AGLD(gmm + tid);          // tid<256: min-ords; tid>=256: max-ords
    #pragma unroll
    for (int m = 1; m < 64; m <<= 1) {
      int o = __shfl_xor(mo, m, 64);
      mo = (sv < 4) ? (mo < o ? mo : o) : (mo > o ? mo : o);
    }
    if (lane == 0) u.mmi[sv] = mo;
  }
  __syncthreads();
  int gmnord = u.mmi[0], gmxord = u.mmi[4];
  #pragma unroll
  for (int g = 1; g < 4; ++g) {
    gmnord = gmnord < u.mmi[g] ? gmnord : u.mmi[g];
    gmxord = gmxord > u.mmi[4 + g] ? gmxord : u.mmi[4 + g];
  }
  const float gmn = ord2f(gmnord);
  const float gmx = ord2f(gmxord);
  const float thr = gmn + 0.1f * (gmx - gmn);

  // ================= A = exp(-2 relu(C-thr)); intra-wave relayout via LDS ==========
#define DECLAM(r) half8 A##r, M##r;
  FOR16(DECLAM)

#define TWRITE { \
    _Float16* reg_ = u.At[sv & 3]; \
    const int q_ = lane >> 4; \
    _Pragma("unroll") \
    for (int c = 0; c < 32; ++c) { \
      _Pragma("unroll") \
      for (int r2 = 0; r2 < 4; ++r2) { \
        float val_ = 1.0f - acc[c][r2]; \
        float a_ = __expf(-2.0f * fmaxf(val_ - thr, 0.0f)); \
        int off_ = (((4 * q_ + r2) * 1024 + (16 * c + fr) * 2) ^ (q_ << 4)) >> 1; \
        reg_[off_] = (_Float16)a_; \
      } \
    } }

#define TREAD(r) { \
    A##r = *(const half8*)((const char*)u.At[sv & 3] + \
            (((r) * 1024 + lane * 16) ^ ((((r) >> 2) & 3) << 4))); \
    M##r = A##r; }

  __syncthreads();
  if (sv < 4) TWRITE
  __syncthreads();
  if (sv < 4) { FOR16(TREAD) }
  __syncthreads();
  if (sv >= 4) TWRITE
  __syncthreads();
  if (sv >= 4) { FOR16(TREAD) }
  __syncthreads();

  // ================= ipot state init =================
  if (tid < 256) *(half2v*)(u.ip.zs + 2 * tid) = (half2v){(_Float16)1.0f, (_Float16)1.0f};
  u.ip.ys[tid] = 1.0f;
  __syncthreads();

  int* mycnt = cnt + b * 16;

  // ================= 30 iterations (r6/r8 proven; fp16 partial exchange) =========
  #pragma unroll 1
  for (int t = 1; t <= 30; ++t) {
    half8 zv = *(const half8*)(u.ip.zs + c0);
    float rp16[16];
#define ROWP(r) { \
      half8 p = M##r * zv; \
      half4 q = p.lo + p.hi; \
      half2v q2 = q.lo + q.hi; \
      rp16[r] = (float)q2.x + (float)q2.y; }
    FOR16(ROWP)
    float c8[8];
    #pragma unroll
    for (int i = 0; i < 8; ++i) {
      float keep = (lane & 1) ? rp16[2*i+1] : rp16[2*i];
      float send = (lane & 1) ? rp16[2*i]   : rp16[2*i+1];
      c8[i] = keep + __shfl_xor(send, 1, 64);
    }
    float c4[4];
    #pragma unroll
    for (int i = 0; i < 4; ++i) {
      float keep = (lane & 2) ? c8[2*i+1] : c8[2*i];
      float send = (lane & 2) ? c8[2*i]   : c8[2*i+1];
      c4[i] = keep + __shfl_xor(send, 2, 64);
    }
    float d2[2];
    #pragma unroll
    for (int i = 0; i < 2; ++i) {
      float keep = (lane & 4) ? c4[2*i+1] : c4[2*i];
      float send = (lane & 4) ? c4[2*i]   : c4[2*i+1];
      d2[i] = keep + __shfl_xor(send, 4, 64);
    }
    float c1;
    {
      float keep = (lane & 8) ? d2[1] : d2[0];
      float send = (lane & 8) ? d2[0] : d2[1];
      c1 = keep + __shfl_xor(send, 8, 64);
    }
    c1 += __shfl_xor(c1, 16, 64);
    c1 += __shfl_xor(c1, 32, 64);
    if (lane < 16) u.ip.xs[r0 + lane] = 1.0f / c1;
    half8 cac = (half8)(_Float16)0.0f;
#define COLP(r) { _Float16 xh = (_Float16)u.ip.xs[r0 + r]; cac += M##r * xh; }
    FOR16(COLP)
    *(half8*)(&u.ip.csh[sv][c0]) = cac;
#define UPDM(r) M##r *= A##r;
    if (t < 30) { FOR16(UPDM) }
    __syncthreads();
    // ---- block col-reduce -> packed fp16 partial (1KB/block) ----
    unsigned* gp = gpart + ((size_t)((t & 1) * 256 + blk) * 256);
    if (tid < 256) {
      float a0 = 0.0f, a1 = 0.0f;
      #pragma unroll
      for (int g = 0; g < 8; ++g) {
        half2v pv = *(const half2v*)(&u.ip.csh[g][2 * tid]);
        a0 += (float)pv.x; a1 += (float)pv.y;
      }
      __half2 ph = __floats2half2_rn(a0, a1);
      AGST(gp + tid, *reinterpret_cast<unsigned*>(&ph));
    }
    __syncthreads();  // s_waitcnt vmcnt(0) before s_barrier: stores at coherent point
    if (tid == 0) {
      __hip_atomic_fetch_add(mycnt, 1, __ATOMIC_RELAXED, __HIP_MEMORY_SCOPE_AGENT);
      while (__hip_atomic_load(mycnt, __ATOMIC_RELAXED, __HIP_MEMORY_SCOPE_AGENT) < 4 * t)
        __builtin_amdgcn_s_sleep(1);
    }
    __syncthreads();
    if (tid < 256) {
      float a0 = 0.0f, a1 = 0.0f;
      #pragma unroll
      for (int q2 = 0; q2 < 4; ++q2) {
        unsigned v = AGLD(gpart + ((size_t)((t & 1) * 256 + b + 64 * q2) * 256) + tid);
        __half2 h = *reinterpret_cast<__half2*>(&v);
        float2 fv = __half22float2(h);
        a0 += fv.x; a1 += fv.y;
      }
      float yo0 = u.ip.ys[2 * tid], yo1 = u.ip.ys[2 * tid + 1];
      float y0 = 1.0f / a0;
      float y1 = 1.0f / a1;
      *(half2v*)(u.ip.zs + 2 * tid) = (half2v){(_Float16)(y0 * y0 / yo0), (_Float16)(y1 * y1 / yo1)};
      u.ip.ys[2 * tid] = y0; u.ip.ys[2 * tid + 1] = y1;
    }
    __syncthreads();
  }

  // ================= dist partial: C' = -0.5 ln A (regs) =================
  float contrib = 0.0f;
#define FINP(r) { \
    float rowacc = 0.0f; \
    rowacc += -0.34657359f * __log2f((float)A##r.s0) * (float)M##r.s0 * u.ip.ys[c0 + 0]; \
    rowacc += -0.34657359f * __log2f((float)A##r.s1) * (float)M##r.s1 * u.ip.ys[c0 + 1]; \
    rowacc += -0.34657359f * __log2f((float)A##r.s2) * (float)M##r.s2 * u.ip.ys[c0 + 2]; \
    rowacc += -0.34657359f * __log2f((float)A##r.s3) * (float)M##r.s3 * u.ip.ys[c0 + 3]; \
    rowacc += -0.34657359f * __log2f((float)A##r.s4) * (float)M##r.s4 * u.ip.ys[c0 + 4]; \
    rowacc += -0.34657359f * __log2f((float)A##r.s5) * (float)M##r.s5 * u.ip.ys[c0 + 5]; \
    rowacc += -0.34657359f * __log2f((float)A##r.s6) * (float)M##r.s6 * u.ip.ys[c0 + 6]; \
    rowacc += -0.34657359f * __log2f((float)A##r.s7) * (float)M##r.s7 * u.ip.ys[c0 + 7]; \
    contrib += rowacc * u.ip.xs[r0 + r]; }
  FOR16(FINP)
  #pragma unroll
  for (int m = 1; m < 64; m <<= 1) contrib += __shfl_xor(contrib, m, 64);
  if (lane == 0) u.ip.wred[sv] = contrib;
  __syncthreads();
  if (tid == 0) {
    float s2 = 0.0f;
    #pragma unroll
    for (int g = 0; g < 8; ++g) s2 += u.ip.wred[g];
    gdist[blk] = s2;
  }
}

// ---------------- K5: deterministic finish: out = -mean_b(dist_b / m) ----------------
__global__ void k_final(const float* __restrict__ gdist, float* __restrict__ out) {
  int b = threadIdx.x & 63;
  float v = gdist[b] + gdist[b + 64] + gdist[b + 128] + gdist[b + 192];
  #pragma unroll
  for (int m = 1; m < 64; m <<= 1) v += __shfl_xor(v, m, 64);
  if (threadIdx.x == 0) out[0] = -v * (1.0f / (64.0f * 512.0f));
}

extern "C" void kernel_launch(void* const* d_in, const int* in_sizes, int n_in,
                              void* d_out, int out_size, void* d_ws, size_t ws_size,
                              hipStream_t stream) {
  const float* f1 = (const float*)d_in[0];
  const float* f2 = (const float*)d_in[1];
  char* ws = (char*)d_ws;
  __half* xn   = (__half*)(ws + 0);                  // 50,331,648 B
  __half* yn   = (__half*)(ws + 50331648);           // 50,331,648 B
  unsigned* gpart = (unsigned*)(ws + 100663296);     // 512KB fp16-packed partials
  int*   meta  = (int*)(ws + 167772160);             // 2 ints
  int*   cnt   = (int*)(ws + 167772160 + 256);       // per-batch cnts + cnt[1024] global
  int*   gmm   = (int*)(ws + 167772160 + 256 + 8192);// 512 ints block min/max
  float* gdist = (float*)(ws + 167772160 + 256 + 8192 + 2048);  // 256 floats

  k_init<<<1, 64, 0, stream>>>(meta, cnt);
  k_norm<<<16384, 256, 0, stream>>>(f1, f2, xn, yn);
  k_main<<<256, 512, 0, stream>>>(xn, yn, meta, cnt, (int*)gmm, gpart, gdist);
  k_final<<<1, 64, 0, stream>>>(gdist, (float*)d_out);
}